// Round 2
// baseline (246.983 us; speedup 1.0000x reference)
//
#include <hip/hip_runtime.h>

// Problem constants (fixed by reference)
#define BB 16
#define CC 256
#define HH 100
#define WW 100
#define NN 100
#define RH 40
#define RW 40
#define KK 599   // num classes
#define KT 19    // ceil(599/32) k-tiles for transpose
#define CT 8     // 256/32 c-tiles

#define NROWS 80        // distinct input rows touched by the 40-output resize
#define RSTRIDE 104     // LDS row stride (floats); 104*4B = 416B, 16B-aligned

// Fused: stream the 80 needed input rows (float4-coalesced) into LDS,
// bilinear-resize 100x100 -> 40x40 (half-pixel) into an LDS tile, per-box
// average pooling via direct region sum (boxes are <=5x5 cells), per-class
// scatter-mean into LDS, write means.
// Row compaction: output row oy needs input rows iy0=(5*oy+1)>>1 and iy0+1;
// these pairs are disjoint across oy, so LDS row 2*oy   <- input row iy0
//                                       LDS row 2*oy+1 <- input row iy0+1.
__global__ __launch_bounds__(256) void pool_kernel(
    const float* __restrict__ feat, const float* __restrict__ boxes,
    const int* __restrict__ cls, float* __restrict__ dst)
{
    __shared__ float rows[NROWS][RSTRIDE];   // 33.3 KB
    __shared__ float tile[RH][RW + 1];       // 6.6 KB
    __shared__ float sums[KK];               // 2.4 KB
    __shared__ float cnts[KK];               // 2.4 KB

    const int blk = blockIdx.x;
    const int b = blk >> 8;       // / 256
    const int c = blk & 255;
    const int tid = threadIdx.x;

    const float* __restrict__ src = feat + (size_t)(b * CC + c) * (HH * WW);

    // ---- stage 80 rows x 100 floats as float4 (2000 x4-loads, all aligned:
    // row byte offset iy*400 is 16B-aligned, plane offset is 16B-aligned) ----
    for (int idx = tid; idx < NROWS * 25; idx += 256) {
        int row = idx / 25;           // LDS row 0..79
        int col4 = idx - row * 25;    // float4 index 0..24
        int p = row >> 1;             // output-row pair 0..39
        int iy = (((5 * p + 1) >> 1)) + (row & 1);
        float4 v = *(const float4*)(src + iy * WW + col4 * 4);
        *(float4*)(&rows[row][col4 * 4]) = v;
    }

    for (int k = tid; k < KK; k += 256) {
        sums[k] = 0.0f;
        cnts[k] = 0.0f;
    }
    __syncthreads();

    // ---- bilinear resize LDS rows -> LDS tile ----
    // src x coord = 2.5*ox + 0.75 ; ix0 = (5*ox+1)>>1 ; frac 0.75/0.25 by parity
    for (int idx = tid; idx < RH * RW; idx += 256) {
        int oy = idx / RW;
        int ox = idx - oy * RW;
        int ix0 = (5 * ox + 1) >> 1;
        float fy = (oy & 1) ? 0.25f : 0.75f;
        float fx = (ox & 1) ? 0.25f : 0.75f;
        const float* r0 = &rows[2 * oy][ix0];
        const float* r1 = &rows[2 * oy + 1][ix0];
        float top = (1.0f - fx) * r0[0] + fx * r0[1];
        float bot = (1.0f - fx) * r1[0] + fx * r1[1];
        tile[oy][ox] = (1.0f - fy) * top + fy * bot;
    }
    __syncthreads();

    // ---- per-box pooling + class scatter (threads 0..99) ----
    if (tid < NN) {
        const float* bp = boxes + (size_t)(b * NN + tid) * 4;
        const float sc = 0.0390625f;  // 40/1024 = 5/128, exact
        // rintf -> v_rndne_f32: round half to even, matches jnp.round
        int x1 = (int)rintf(bp[0] * sc);
        int y1 = (int)rintf(bp[1] * sc);
        int x2 = (int)rintf(bp[2] * sc);
        int y2 = (int)rintf(bp[3] * sc);
        x1 = max(x1, 0); y1 = max(y1, 0);
        x2 = min(x2, RW); y2 = min(y2, RH);
        if (x1 < x2 && y1 < y2) {
            float s = 0.0f;
            for (int y = y1; y < y2; ++y)
                for (int x = x1; x < x2; ++x)
                    s += tile[y][x];
            float area = (float)((y2 - y1) * (x2 - x1));
            int k = cls[b * NN + tid];
            atomicAdd(&sums[k], s / area);
            atomicAdd(&cnts[k], 1.0f);
        }
    }
    __syncthreads();

    // ---- write per-class means, ws layout [b][c][k] (coalesced) ----
    float* o = dst + (size_t)(b * CC + c) * KK;
    for (int k = tid; k < KK; k += 256) {
        float cn = cnts[k];
        o[k] = (cn > 0.0f) ? (sums[k] / cn) : 0.0f;
    }
}

// Transpose ws[b][c][k] -> out[b][k][c], 32x32 LDS tiles, both sides coalesced.
__global__ __launch_bounds__(256) void transpose_kernel(
    const float* __restrict__ ws, float* __restrict__ out)
{
    __shared__ float t[32][33];
    int blk = blockIdx.x;
    int b = blk / (KT * CT);
    int r = blk - b * (KT * CT);
    int kt = r / CT;
    int ct = r - kt * CT;
    int k0 = kt * 32;
    int c0 = ct * 32;
    int tx = threadIdx.x & 31;
    int ty = threadIdx.x >> 5;  // 0..7

    int k = k0 + tx;
    if (k < KK) {
        #pragma unroll
        for (int i = 0; i < 4; ++i) {
            int cl = ty + i * 8;
            t[cl][tx] = ws[(size_t)(b * CC + c0 + cl) * KK + k];
        }
    }
    __syncthreads();
    #pragma unroll
    for (int i = 0; i < 4; ++i) {
        int kl = ty + i * 8;
        int kk = k0 + kl;
        if (kk < KK)
            out[(size_t)(b * KK + kk) * CC + c0 + tx] = t[tx][kl];
    }
}

extern "C" void kernel_launch(void* const* d_in, const int* in_sizes, int n_in,
                              void* d_out, int out_size, void* d_ws, size_t ws_size,
                              hipStream_t stream) {
    const float* feat  = (const float*)d_in[0];
    const float* boxes = (const float*)d_in[1];
    const int*   cls   = (const int*)d_in[2];
    float* out = (float*)d_out;
    float* ws = (float*)d_ws;

    pool_kernel<<<BB * CC, 256, 0, stream>>>(feat, boxes, cls, ws);
    transpose_kernel<<<BB * KT * CT, 256, 0, stream>>>(ws, out);
}